// Round 4
// baseline (416.053 us; speedup 1.0000x reference)
//
#include <hip/hip_runtime.h>
#include <math.h>

typedef __attribute__((ext_vector_type(8))) __bf16 bf16x8;
typedef __attribute__((ext_vector_type(4))) float f32x4;
typedef __attribute__((ext_vector_type(8))) unsigned short u16x8;
typedef __attribute__((ext_vector_type(8))) int i32x8;

#define GAS(p) ((const __attribute__((address_space(1))) void*)(p))
#define LAS(p) ((__attribute__((address_space(3))) void*)(p))

__device__ __forceinline__ unsigned short f2bf(float f) {
  union { float f; unsigned int u; } v; v.f = f;
  unsigned int r = (v.u + 0x7FFFu + ((v.u >> 16) & 1u)) >> 16;
  return (unsigned short)r;
}
__device__ __forceinline__ float bf2f(unsigned short b) {
  union { unsigned int u; float f; } v; v.u = ((unsigned int)b) << 16;
  return v.f;
}

// ---------------- fused f32 -> bf16 cast for z1,z2,w1,w2 ----------------
__global__ __launch_bounds__(256) void cast_all_kernel(
    const float* __restrict__ z1, const float* __restrict__ z2,
    const float* __restrict__ w1, const float* __restrict__ w2,
    unsigned short* __restrict__ z1b, unsigned short* __restrict__ z2b,
    unsigned short* __restrict__ w1b, unsigned short* __restrict__ w2b) {
  int b = blockIdx.x;
  const float* in; unsigned short* out; int base;
  if (b < 4096)       { in = z1; out = z1b; base = b; }
  else if (b < 8192)  { in = z2; out = z2b; base = b - 4096; }
  else if (b < 8448)  { in = w1; out = w1b; base = b - 8192; }
  else                { in = w2; out = w2b; base = b - 8448; }
  int i = (base * 256 + threadIdx.x) * 4;
  float4 v = *(const float4*)(in + i);
  ushort4 o;
  o.x = f2bf(v.x); o.y = f2bf(v.y); o.z = f2bf(v.z); o.w = f2bf(v.w);
  *(ushort4*)(out + i) = o;
}

// ---------------- core 128x128 NT bf16 tile, K=512 (projections) ----------------
__device__ __forceinline__ void gemm_tile_512(
    const unsigned short* __restrict__ A, const unsigned short* __restrict__ B,
    int m0, int n0, unsigned short* lA, unsigned short* lB, f32x4 acc[4][4]) {
  constexpr int K = 512;
  const int tid  = threadIdx.x;
  const int wave = tid >> 6;
  const int lane = tid & 63;
  const int quad = lane >> 4;
  const int l16  = lane & 15;
  const int wrow = (wave & 1) * 64;
  const int wcol = (wave >> 1) * 64;

  const f32x4 zero = {0.f, 0.f, 0.f, 0.f};
#pragma unroll
  for (int i = 0; i < 4; ++i)
#pragma unroll
    for (int j = 0; j < 4; ++j) acc[i][j] = zero;

  const int e0 = wave * 1024 + lane * 8;
  const int r0 = e0 >> 5, c0 = e0 & 31;
  const int e1 = e0 + 512;
  const int r1 = e1 >> 5, c1 = e1 & 31;

  const unsigned short* Ag0 = A + (size_t)(m0 + r0) * K + c0;
  const unsigned short* Ag1 = A + (size_t)(m0 + r1) * K + c1;
  const unsigned short* Bg0 = B + (size_t)(n0 + r0) * K + c0;
  const unsigned short* Bg1 = B + (size_t)(n0 + r1) * K + c1;

  for (int kt = 0; kt < K; kt += 32) {
    __syncthreads();
    __builtin_amdgcn_global_load_lds(GAS(Ag0 + kt), LAS(&lA[e0]), 16, 0, 0);
    __builtin_amdgcn_global_load_lds(GAS(Ag1 + kt), LAS(&lA[e1]), 16, 0, 0);
    __builtin_amdgcn_global_load_lds(GAS(Bg0 + kt), LAS(&lB[e0]), 16, 0, 0);
    __builtin_amdgcn_global_load_lds(GAS(Bg1 + kt), LAS(&lB[e1]), 16, 0, 0);
    __syncthreads();

    bf16x8 af[4], bfr[4];
#pragma unroll
    for (int i = 0; i < 4; ++i) {
      af[i]  = *(const bf16x8*)&lA[(wrow + i * 16 + l16) * 32 + quad * 8];
      bfr[i] = *(const bf16x8*)&lB[(wcol + i * 16 + l16) * 32 + quad * 8];
    }
#pragma unroll
    for (int mi = 0; mi < 4; ++mi)
#pragma unroll
      for (int ni = 0; ni < 4; ++ni)
        acc[mi][ni] = __builtin_amdgcn_mfma_f32_16x16x32_bf16(
            af[mi], bfr[ni], acc[mi][ni], 0, 0, 0);
  }
}

// ---------------- fused projection GEMM (2 inputs per launch) ----------------
template<int EPI>
__global__ __launch_bounds__(256)
void proj_kernel(const unsigned short* __restrict__ A1,
                 const unsigned short* __restrict__ A2,
                 const unsigned short* __restrict__ W,
                 const float* __restrict__ bias,
                 unsigned short* __restrict__ C1,
                 unsigned short* __restrict__ C2) {
  __shared__ unsigned short lA[128 * 32];
  __shared__ unsigned short lB[128 * 32];
  const int b = blockIdx.x;
  const int which = b >> 8;
  const int r = b & 255;
  const int n0 = (r & 3) * 128;
  const int m0 = (r >> 2) * 128;
  const unsigned short* A = which ? A2 : A1;
  unsigned short* C = which ? C2 : C1;

  f32x4 acc[4][4];
  gemm_tile_512(A, W, m0, n0, lA, lB, acc);

  const int lane = threadIdx.x & 63;
  const int wave = threadIdx.x >> 6;
  const int quad = lane >> 4;
  const int l16  = lane & 15;
  const int wrow = (wave & 1) * 64;
  const int wcol = (wave >> 1) * 64;

#pragma unroll
  for (int ni = 0; ni < 4; ++ni) {
    const int c = n0 + wcol + ni * 16 + l16;
    const float bv = bias[c];
#pragma unroll
    for (int mi = 0; mi < 4; ++mi) {
      const int rbase = m0 + wrow + mi * 16 + quad * 4;
#pragma unroll
      for (int rr = 0; rr < 4; ++rr) {
        float v = acc[mi][ni][rr] + bv;
        if constexpr (EPI == 0) v = (v > 0.f) ? v : expm1f(v);
        C[(size_t)(rbase + rr) * 512 + c] = f2bf(v);
      }
    }
  }
}

// ---------------- LDS-free MX-fp8 Gram kernel ----------------
// No __shared__, no barriers. Each wave streams its A/B fragments directly
// from global (L1/L2-resident, 8 MB total) with a register double-buffer:
// issue chunk k+1's 16 global_load_dwordx4, MFMA chunk k (553 cyc) hides
// the ~200-400 cyc L2 latency. Fragment layout = verified 16x16x128 mapping:
// A[row=lane&15][k = quad*32 + j], offsets are immediates (row stride 512B).
__global__ __launch_bounds__(256)
void gram_kernel(const unsigned char* __restrict__ q1,
                 const unsigned char* __restrict__ q2,
                 float* __restrict__ d11, float* __restrict__ d22,
                 float* __restrict__ d12r, float* __restrict__ d12c) {
  const int b = blockIdx.x;
  const unsigned char *A, *B;
  float *rsum, *csum;
  int m0, n0;
  if (b < 4160) {
    const bool first = (b < 2080);
    const unsigned char* h = first ? q1 : q2;
    float* d = first ? d11 : d22;
    int t = first ? b : b - 2080;
    int by = (int)((sqrtf(8.f * t + 1.f) - 1.f) * 0.5f);
    while ((by + 1) * (by + 2) / 2 <= t) ++by;
    while (by * (by + 1) / 2 > t) --by;
    int bx = t - by * (by + 1) / 2;
    A = h; B = h; m0 = by * 128; n0 = bx * 128;
    rsum = d; csum = (bx == by) ? nullptr : d;
  } else {
    int t = b - 4160;
    m0 = (t >> 6) * 128; n0 = (t & 63) * 128;
    A = q1; B = q2; rsum = d12r; csum = d12c;
  }

  const int tid  = threadIdx.x;
  const int wave = tid >> 6;
  const int lane = tid & 63;
  const int quad = lane >> 4;
  const int l16  = lane & 15;
  const int wrow = (wave & 1) * 64;
  const int wcol = (wave >> 1) * 64;

  const f32x4 zero = {0.f, 0.f, 0.f, 0.f};
  f32x4 acc[4][4];
#pragma unroll
  for (int i = 0; i < 4; ++i)
#pragma unroll
    for (int j = 0; j < 4; ++j) acc[i][j] = zero;

  // per-mi fragment base pointers (include lane row + quad k-offset)
  const unsigned char* Ap[4];
  const unsigned char* Bp[4];
#pragma unroll
  for (int i = 0; i < 4; ++i) {
    Ap[i] = A + (size_t)(m0 + wrow + i * 16 + l16) * 512 + quad * 32;
    Bp[i] = B + (size_t)(n0 + wcol + i * 16 + l16) * 512 + quad * 32;
  }

  union frag { i32x8 v; int4 h[2]; };
  frag fa[2][4], fb[2][4];

  // prologue: chunk 0 into buffer 0
#pragma unroll
  for (int i = 0; i < 4; ++i) {
    fa[0][i].h[0] = *(const int4*)(Ap[i]);
    fa[0][i].h[1] = *(const int4*)(Ap[i] + 16);
    fb[0][i].h[0] = *(const int4*)(Bp[i]);
    fb[0][i].h[1] = *(const int4*)(Bp[i] + 16);
  }

#pragma unroll
  for (int c = 0; c < 4; ++c) {
    const int cur = c & 1, nxt = cur ^ 1;
    if (c < 3) {
      const int off = (c + 1) * 128;
#pragma unroll
      for (int i = 0; i < 4; ++i) {
        fa[nxt][i].h[0] = *(const int4*)(Ap[i] + off);
        fa[nxt][i].h[1] = *(const int4*)(Ap[i] + off + 16);
        fb[nxt][i].h[0] = *(const int4*)(Bp[i] + off);
        fb[nxt][i].h[1] = *(const int4*)(Bp[i] + off + 16);
      }
    }
#pragma unroll
    for (int mi = 0; mi < 4; ++mi)
#pragma unroll
      for (int ni = 0; ni < 4; ++ni)
        acc[mi][ni] = __builtin_amdgcn_mfma_scale_f32_16x16x128_f8f6f4(
            fa[cur][mi].v, fb[cur][ni].v, acc[mi][ni],
            0, 0,                    // cbsz=e4m3, blgp=e4m3
            0, 0x7F7F7F7F,           // scale_a (E8M0 1.0)
            0, 0x7F7F7F7F);          // scale_b
  }

  // epilogue: C/D layout shape-determined: col=lane&15, row=quad*4+reg
  float cs[4] = {0.f, 0.f, 0.f, 0.f};
#pragma unroll
  for (int mi = 0; mi < 4; ++mi) {
    float rs[4] = {0.f, 0.f, 0.f, 0.f};
#pragma unroll
    for (int ni = 0; ni < 4; ++ni) {
#pragma unroll
      for (int rr = 0; rr < 4; ++rr) {
        float v = __expf(2.0f * acc[mi][ni][rr]);
        rs[rr] += v;
        cs[ni] += v;
      }
    }
#pragma unroll
    for (int d = 1; d < 16; d <<= 1) {
#pragma unroll
      for (int rr = 0; rr < 4; ++rr) rs[rr] += __shfl_xor(rs[rr], d, 64);
    }
    if (l16 == 0) {
      const int rbase = m0 + wrow + mi * 16 + quad * 4;
#pragma unroll
      for (int rr = 0; rr < 4; ++rr) atomicAdd(&rsum[rbase + rr], rs[rr]);
    }
  }
  if (csum) {
#pragma unroll
    for (int ni = 0; ni < 4; ++ni) {
      float v = cs[ni];
      v += __shfl_xor(v, 16, 64);
      v += __shfl_xor(v, 32, 64);
      if (quad == 0) atomicAdd(&csum[n0 + wcol + ni * 16 + l16], v);
    }
  }
}

// ---------------- normalize -> fp8 (q1,q2) + diag dot ----------------
__global__ __launch_bounds__(256)
void norm_diag_kernel(const unsigned short* __restrict__ h1,
                      const unsigned short* __restrict__ h2,
                      unsigned char* __restrict__ q1,
                      unsigned char* __restrict__ q2,
                      float* __restrict__ cdiag) {
  const int wave = threadIdx.x >> 6, lane = threadIdx.x & 63;
  const int row = blockIdx.x * 4 + wave;
  const u16x8 u1 = *(const u16x8*)(h1 + (size_t)row * 512 + lane * 8);
  const u16x8 u2 = *(const u16x8*)(h2 + (size_t)row * 512 + lane * 8);
  float f1[8], f2[8], ss1 = 0.f, ss2 = 0.f;
#pragma unroll
  for (int j = 0; j < 8; ++j) {
    f1[j] = bf2f(u1[j]); ss1 += f1[j] * f1[j];
    f2[j] = bf2f(u2[j]); ss2 += f2[j] * f2[j];
  }
#pragma unroll
  for (int d = 1; d < 64; d <<= 1) {
    ss1 += __shfl_xor(ss1, d, 64);
    ss2 += __shfl_xor(ss2, d, 64);
  }
  const float inv1 = 1.0f / fmaxf(sqrtf(ss1), 1e-12f);
  const float inv2 = 1.0f / fmaxf(sqrtf(ss2), 1e-12f);
  float a[8], bb[8];
  float dot = 0.f;
#pragma unroll
  for (int j = 0; j < 8; ++j) {
    a[j] = f1[j] * inv1; bb[j] = f2[j] * inv2;
    dot += a[j] * bb[j];
  }
  int lo1 = __builtin_amdgcn_cvt_pk_fp8_f32(a[0], a[1], 0, false);
  lo1 = __builtin_amdgcn_cvt_pk_fp8_f32(a[2], a[3], lo1, true);
  int hi1 = __builtin_amdgcn_cvt_pk_fp8_f32(a[4], a[5], 0, false);
  hi1 = __builtin_amdgcn_cvt_pk_fp8_f32(a[6], a[7], hi1, true);
  int lo2 = __builtin_amdgcn_cvt_pk_fp8_f32(bb[0], bb[1], 0, false);
  lo2 = __builtin_amdgcn_cvt_pk_fp8_f32(bb[2], bb[3], lo2, true);
  int hi2 = __builtin_amdgcn_cvt_pk_fp8_f32(bb[4], bb[5], 0, false);
  hi2 = __builtin_amdgcn_cvt_pk_fp8_f32(bb[6], bb[7], hi2, true);
  *(int2*)(q1 + (size_t)row * 512 + lane * 8) = make_int2(lo1, hi1);
  *(int2*)(q2 + (size_t)row * 512 + lane * 8) = make_int2(lo2, hi2);
#pragma unroll
  for (int d = 1; d < 64; d <<= 1) dot += __shfl_xor(dot, d, 64);
  if (lane == 0) cdiag[row] = dot;
}

// ---------------- final scalar loss ----------------
__global__ __launch_bounds__(256)
void finalize_kernel(const float* __restrict__ d11, const float* __restrict__ d22,
                     const float* __restrict__ d12r, const float* __restrict__ d12c,
                     const float* __restrict__ cdiag, float* __restrict__ out) {
  const float e2 = 7.38905609893065f;
  float s = 0.f;
  for (int i = threadIdx.x; i < 8192; i += 256) {
    const float den1 = d11[i] + d12r[i] - e2;
    const float den2 = d22[i] + d12c[i] - e2;
    s += -2.0f * cdiag[i] + 0.5f * (logf(den1) + logf(den2));
  }
#pragma unroll
  for (int d = 1; d < 64; d <<= 1) s += __shfl_xor(s, d, 64);
  __shared__ float sm[4];
  if ((threadIdx.x & 63) == 0) sm[threadIdx.x >> 6] = s;
  __syncthreads();
  if (threadIdx.x == 0) out[0] = (sm[0] + sm[1] + sm[2] + sm[3]) * (1.0f / 8192.0f);
}

extern "C" void kernel_launch(void* const* d_in, const int* in_sizes, int n_in,
                              void* d_out, int out_size, void* d_ws, size_t ws_size,
                              hipStream_t stream) {
  const float* z1 = (const float*)d_in[0];
  const float* z2 = (const float*)d_in[1];
  const float* w1 = (const float*)d_in[2];
  const float* b1 = (const float*)d_in[3];
  const float* w2 = (const float*)d_in[4];
  const float* b2 = (const float*)d_in[5];
  float* out = (float*)d_out;

  const int N = 8192, D = 512;
  char* ws = (char*)d_ws;
  auto alloc = [&](size_t bytes) {
    char* p = ws; ws += (bytes + 255) & ~(size_t)255; return p;
  };
  unsigned short* z1b = (unsigned short*)alloc((size_t)N * D * 2);
  unsigned short* z2b = (unsigned short*)alloc((size_t)N * D * 2);
  unsigned short* g1  = (unsigned short*)alloc((size_t)N * D * 2);
  unsigned short* g2  = (unsigned short*)alloc((size_t)N * D * 2);
  unsigned short* w1b = (unsigned short*)alloc((size_t)D * D * 2);
  unsigned short* w2b = (unsigned short*)alloc((size_t)D * D * 2);
  float* sums  = (float*)alloc((size_t)4 * N * sizeof(float));
  float* cdiag = (float*)alloc((size_t)N * sizeof(float));
  float* d11 = sums, *d22 = sums + N, *d12r = sums + 2 * N, *d12c = sums + 3 * N;
  unsigned short* h1 = z1b;                 // stage-2 out aliases z buffers
  unsigned short* h2 = z2b;
  unsigned char* q1 = (unsigned char*)g1;   // fp8 aliases g (dead after proj2)
  unsigned char* q2 = (unsigned char*)g2;

  hipMemsetAsync(sums, 0, (size_t)4 * N * sizeof(float), stream);

  cast_all_kernel<<<dim3(8704), 256, 0, stream>>>(z1, z2, w1, w2, z1b, z2b, w1b, w2b);
  proj_kernel<0><<<dim3(512), 256, 0, stream>>>(z1b, z2b, w1b, b1, g1, g2);
  proj_kernel<1><<<dim3(512), 256, 0, stream>>>(g1, g2, w2b, b2, h1, h2);
  norm_diag_kernel<<<dim3(N / 4), 256, 0, stream>>>(h1, h2, q1, q2, cdiag);
  gram_kernel<<<dim3(8256), 256, 0, stream>>>(q1, q2, d11, d22, d12r, d12c);
  finalize_kernel<<<1, 256, 0, stream>>>(d11, d22, d12r, d12c, cdiag, out);
}

// Round 5
// 373.642 us; speedup vs baseline: 1.1135x; 1.1135x over previous
//
#include <hip/hip_runtime.h>
#include <math.h>

typedef __attribute__((ext_vector_type(8))) __bf16 bf16x8;
typedef __attribute__((ext_vector_type(4))) float f32x4;
typedef __attribute__((ext_vector_type(8))) unsigned short u16x8;
typedef __attribute__((ext_vector_type(8))) int i32x8;

#define GAS(p) ((const __attribute__((address_space(1))) void*)(p))
#define LAS(p) ((__attribute__((address_space(3))) void*)(p))

__device__ __forceinline__ unsigned short f2bf(float f) {
  union { float f; unsigned int u; } v; v.f = f;
  unsigned int r = (v.u + 0x7FFFu + ((v.u >> 16) & 1u)) >> 16;
  return (unsigned short)r;
}
__device__ __forceinline__ float bf2f(unsigned short b) {
  union { unsigned int u; float f; } v; v.u = ((unsigned int)b) << 16;
  return v.f;
}

// ---------------- fused f32 -> bf16 cast for z1,z2,w1,w2 ----------------
__global__ __launch_bounds__(256) void cast_all_kernel(
    const float* __restrict__ z1, const float* __restrict__ z2,
    const float* __restrict__ w1, const float* __restrict__ w2,
    unsigned short* __restrict__ z1b, unsigned short* __restrict__ z2b,
    unsigned short* __restrict__ w1b, unsigned short* __restrict__ w2b) {
  int b = blockIdx.x;
  const float* in; unsigned short* out; int base;
  if (b < 4096)       { in = z1; out = z1b; base = b; }
  else if (b < 8192)  { in = z2; out = z2b; base = b - 4096; }
  else if (b < 8448)  { in = w1; out = w1b; base = b - 8192; }
  else                { in = w2; out = w2b; base = b - 8448; }
  int i = (base * 256 + threadIdx.x) * 4;
  float4 v = *(const float4*)(in + i);
  ushort4 o;
  o.x = f2bf(v.x); o.y = f2bf(v.y); o.z = f2bf(v.z); o.w = f2bf(v.w);
  *(ushort4*)(out + i) = o;
}

// ---------------- core 128x128 NT bf16 tile, K=512 (projections) ----------------
__device__ __forceinline__ void gemm_tile_512(
    const unsigned short* __restrict__ A, const unsigned short* __restrict__ B,
    int m0, int n0, unsigned short* lA, unsigned short* lB, f32x4 acc[4][4]) {
  constexpr int K = 512;
  const int tid  = threadIdx.x;
  const int wave = tid >> 6;
  const int lane = tid & 63;
  const int quad = lane >> 4;
  const int l16  = lane & 15;
  const int wrow = (wave & 1) * 64;
  const int wcol = (wave >> 1) * 64;

  const f32x4 zero = {0.f, 0.f, 0.f, 0.f};
#pragma unroll
  for (int i = 0; i < 4; ++i)
#pragma unroll
    for (int j = 0; j < 4; ++j) acc[i][j] = zero;

  const int e0 = wave * 1024 + lane * 8;
  const int r0 = e0 >> 5, c0 = e0 & 31;
  const int e1 = e0 + 512;
  const int r1 = e1 >> 5, c1 = e1 & 31;

  const unsigned short* Ag0 = A + (size_t)(m0 + r0) * K + c0;
  const unsigned short* Ag1 = A + (size_t)(m0 + r1) * K + c1;
  const unsigned short* Bg0 = B + (size_t)(n0 + r0) * K + c0;
  const unsigned short* Bg1 = B + (size_t)(n0 + r1) * K + c1;

  for (int kt = 0; kt < K; kt += 32) {
    __syncthreads();
    __builtin_amdgcn_global_load_lds(GAS(Ag0 + kt), LAS(&lA[e0]), 16, 0, 0);
    __builtin_amdgcn_global_load_lds(GAS(Ag1 + kt), LAS(&lA[e1]), 16, 0, 0);
    __builtin_amdgcn_global_load_lds(GAS(Bg0 + kt), LAS(&lB[e0]), 16, 0, 0);
    __builtin_amdgcn_global_load_lds(GAS(Bg1 + kt), LAS(&lB[e1]), 16, 0, 0);
    __syncthreads();

    bf16x8 af[4], bfr[4];
#pragma unroll
    for (int i = 0; i < 4; ++i) {
      af[i]  = *(const bf16x8*)&lA[(wrow + i * 16 + l16) * 32 + quad * 8];
      bfr[i] = *(const bf16x8*)&lB[(wcol + i * 16 + l16) * 32 + quad * 8];
    }
#pragma unroll
    for (int mi = 0; mi < 4; ++mi)
#pragma unroll
      for (int ni = 0; ni < 4; ++ni)
        acc[mi][ni] = __builtin_amdgcn_mfma_f32_16x16x32_bf16(
            af[mi], bfr[ni], acc[mi][ni], 0, 0, 0);
  }
}

// ---------------- fused projection GEMM (2 inputs per launch) ----------------
template<int EPI>
__global__ __launch_bounds__(256)
void proj_kernel(const unsigned short* __restrict__ A1,
                 const unsigned short* __restrict__ A2,
                 const unsigned short* __restrict__ W,
                 const float* __restrict__ bias,
                 unsigned short* __restrict__ C1,
                 unsigned short* __restrict__ C2) {
  __shared__ unsigned short lA[128 * 32];
  __shared__ unsigned short lB[128 * 32];
  const int b = blockIdx.x;
  const int which = b >> 8;
  const int r = b & 255;
  const int n0 = (r & 3) * 128;
  const int m0 = (r >> 2) * 128;
  const unsigned short* A = which ? A2 : A1;
  unsigned short* C = which ? C2 : C1;

  f32x4 acc[4][4];
  gemm_tile_512(A, W, m0, n0, lA, lB, acc);

  const int lane = threadIdx.x & 63;
  const int wave = threadIdx.x >> 6;
  const int quad = lane >> 4;
  const int l16  = lane & 15;
  const int wrow = (wave & 1) * 64;
  const int wcol = (wave >> 1) * 64;

#pragma unroll
  for (int ni = 0; ni < 4; ++ni) {
    const int c = n0 + wcol + ni * 16 + l16;
    const float bv = bias[c];
#pragma unroll
    for (int mi = 0; mi < 4; ++mi) {
      const int rbase = m0 + wrow + mi * 16 + quad * 4;
#pragma unroll
      for (int rr = 0; rr < 4; ++rr) {
        float v = acc[mi][ni][rr] + bv;
        if constexpr (EPI == 0) v = (v > 0.f) ? v : expm1f(v);
        C[(size_t)(rbase + rr) * 512 + c] = f2bf(v);
      }
    }
  }
}

// ================= pipelined MX-fp8 Gram kernel =================
// Persistent blocks: 1032 blocks x 8 tiles. Chunk-level LDS double buffer
// (2 x (16KB A + 16KB B) = 64KB): staging for chunk c+1 is issued BEFORE
// compute of chunk c, so the vmcnt drain at the end-of-chunk barrier lands
// ~1 chunk-compute after issue (L2 latency fully hidden). Buffers alternate
// seamlessly across tile boundaries (parity = kt&1, 4 chunks/tile).

struct TileDesc {
  const unsigned char* A;
  const unsigned char* B;
  float* rsum;
  float* csum;
  int m0, n0;
};

__device__ __forceinline__ TileDesc decode_tile(
    int t, const unsigned char* q1, const unsigned char* q2,
    float* d11, float* d22, float* d12r, float* d12c) {
  TileDesc d;
  if (t < 4160) {
    const bool first = (t < 2080);
    const unsigned char* h = first ? q1 : q2;
    float* dd = first ? d11 : d22;
    int u = first ? t : t - 2080;
    int by = (int)((sqrtf(8.f * u + 1.f) - 1.f) * 0.5f);
    while ((by + 1) * (by + 2) / 2 <= u) ++by;
    while (by * (by + 1) / 2 > u) --by;
    int bx = u - by * (by + 1) / 2;
    d.A = h; d.B = h; d.m0 = by * 128; d.n0 = bx * 128;
    d.rsum = dd; d.csum = (bx == by) ? nullptr : dd;
  } else {
    int u = t - 4160;
    d.m0 = (u >> 6) * 128; d.n0 = (u & 63) * 128;
    d.A = q1; d.B = q2; d.rsum = d12r; d.csum = d12c;
  }
  return d;
}

__device__ __forceinline__ void stage_chunk(
    const TileDesc& d, int kt, unsigned char* bufA, unsigned char* bufB,
    int srow, int sblk, int ldst) {
  const unsigned char* Ab = d.A + (size_t)(d.m0 + srow) * 512 + sblk * 16 + kt * 128;
  const unsigned char* Bb = d.B + (size_t)(d.n0 + srow) * 512 + sblk * 16 + kt * 128;
#pragma unroll
  for (int t = 0; t < 4; ++t) {
    __builtin_amdgcn_global_load_lds(GAS(Ab + t * 8 * 512),
                                     LAS(bufA + ldst + t * 1024), 16, 0, 0);
    __builtin_amdgcn_global_load_lds(GAS(Bb + t * 8 * 512),
                                     LAS(bufB + ldst + t * 1024), 16, 0, 0);
  }
}

__global__ __launch_bounds__(256)
void gram_kernel(const unsigned char* __restrict__ q1,
                 const unsigned char* __restrict__ q2,
                 float* __restrict__ d11, float* __restrict__ d22,
                 float* __restrict__ d12r, float* __restrict__ d12c) {
  __shared__ unsigned char lA[2][128 * 128];
  __shared__ unsigned char lB[2][128 * 128];

  const int tid  = threadIdx.x;
  const int wave = tid >> 6;
  const int lane = tid & 63;
  const int quad = lane >> 4;
  const int l16  = lane & 15;
  const int wrow = (wave & 1) * 64;
  const int wcol = (wave >> 1) * 64;

  // staging address pattern (XOR-swizzled source, wave-uniform LDS dest)
  const int srow = wave * 32 + (lane >> 3);
  const int sblk = (lane & 7) ^ ((lane >> 3) & 7);
  const int ldst = wave * 4096 + lane * 16;

  union frag { i32x8 v; int4 h[2]; };
  const f32x4 zero = {0.f, 0.f, 0.f, 0.f};

  TileDesc cur = decode_tile(blockIdx.x * 8, q1, q2, d11, d22, d12r, d12c);
  stage_chunk(cur, 0, lA[0], lB[0], srow, sblk, ldst);
  __syncthreads();

  for (int j = 0; j < 8; ++j) {
    const bool have_nxt = (j < 7);
    TileDesc nxt;
    if (have_nxt)
      nxt = decode_tile(blockIdx.x * 8 + j + 1, q1, q2, d11, d22, d12r, d12c);

    f32x4 acc[4][4];
#pragma unroll
    for (int i = 0; i < 4; ++i)
#pragma unroll
      for (int jj = 0; jj < 4; ++jj) acc[i][jj] = zero;

#pragma unroll
    for (int kt = 0; kt < 4; ++kt) {
      // issue next chunk's staging into the other buffer
      if (kt < 3) {
        stage_chunk(cur, kt + 1, lA[(kt + 1) & 1], lB[(kt + 1) & 1],
                    srow, sblk, ldst);
      } else if (have_nxt) {
        stage_chunk(nxt, 0, lA[0], lB[0], srow, sblk, ldst);
      }
      // compute current chunk from buf[kt&1]
      const unsigned char* cA = lA[kt & 1];
      const unsigned char* cB = lB[kt & 1];
      frag fa[4], fb[4];
#pragma unroll
      for (int i = 0; i < 4; ++i) {
        const int ra = wrow + i * 16 + l16;
        const int pa = ra & 7;
        fa[i].h[0] = *(const int4*)&cA[ra * 128 + ((2 * quad)     ^ pa) * 16];
        fa[i].h[1] = *(const int4*)&cA[ra * 128 + ((2 * quad + 1) ^ pa) * 16];
        const int rb = wcol + i * 16 + l16;
        const int pb = rb & 7;
        fb[i].h[0] = *(const int4*)&cB[rb * 128 + ((2 * quad)     ^ pb) * 16];
        fb[i].h[1] = *(const int4*)&cB[rb * 128 + ((2 * quad + 1) ^ pb) * 16];
      }
#pragma unroll
      for (int mi = 0; mi < 4; ++mi)
#pragma unroll
        for (int ni = 0; ni < 4; ++ni)
          acc[mi][ni] = __builtin_amdgcn_mfma_scale_f32_16x16x128_f8f6f4(
              fa[mi].v, fb[ni].v, acc[mi][ni],
              0, 0,                    // cbsz=e4m3, blgp=e4m3
              0, 0x7F7F7F7F,           // scale_a (E8M0 1.0)
              0, 0x7F7F7F7F);          // scale_b
      __syncthreads();
    }

    // epilogue: C/D layout: col=lane&15, row=quad*4+reg
    float cs[4] = {0.f, 0.f, 0.f, 0.f};
#pragma unroll
    for (int mi = 0; mi < 4; ++mi) {
      float rs[4] = {0.f, 0.f, 0.f, 0.f};
#pragma unroll
      for (int ni = 0; ni < 4; ++ni) {
#pragma unroll
        for (int rr = 0; rr < 4; ++rr) {
          float v = __expf(2.0f * acc[mi][ni][rr]);
          rs[rr] += v;
          cs[ni] += v;
        }
      }
#pragma unroll
      for (int d = 1; d < 16; d <<= 1) {
#pragma unroll
        for (int rr = 0; rr < 4; ++rr) rs[rr] += __shfl_xor(rs[rr], d, 64);
      }
      if (l16 == 0) {
        const int rbase = cur.m0 + wrow + mi * 16 + quad * 4;
#pragma unroll
        for (int rr = 0; rr < 4; ++rr) atomicAdd(&cur.rsum[rbase + rr], rs[rr]);
      }
    }
    if (cur.csum) {
#pragma unroll
      for (int ni = 0; ni < 4; ++ni) {
        float v = cs[ni];
        v += __shfl_xor(v, 16, 64);
        v += __shfl_xor(v, 32, 64);
        if (quad == 0) atomicAdd(&cur.csum[cur.n0 + wcol + ni * 16 + l16], v);
      }
    }
    cur = nxt;
  }
}

// ---------------- normalize -> fp8 (q1,q2) + diag dot ----------------
__global__ __launch_bounds__(256)
void norm_diag_kernel(const unsigned short* __restrict__ h1,
                      const unsigned short* __restrict__ h2,
                      unsigned char* __restrict__ q1,
                      unsigned char* __restrict__ q2,
                      float* __restrict__ cdiag) {
  const int wave = threadIdx.x >> 6, lane = threadIdx.x & 63;
  const int row = blockIdx.x * 4 + wave;
  const u16x8 u1 = *(const u16x8*)(h1 + (size_t)row * 512 + lane * 8);
  const u16x8 u2 = *(const u16x8*)(h2 + (size_t)row * 512 + lane * 8);
  float f1[8], f2[8], ss1 = 0.f, ss2 = 0.f;
#pragma unroll
  for (int j = 0; j < 8; ++j) {
    f1[j] = bf2f(u1[j]); ss1 += f1[j] * f1[j];
    f2[j] = bf2f(u2[j]); ss2 += f2[j] * f2[j];
  }
#pragma unroll
  for (int d = 1; d < 64; d <<= 1) {
    ss1 += __shfl_xor(ss1, d, 64);
    ss2 += __shfl_xor(ss2, d, 64);
  }
  const float inv1 = 1.0f / fmaxf(sqrtf(ss1), 1e-12f);
  const float inv2 = 1.0f / fmaxf(sqrtf(ss2), 1e-12f);
  float a[8], bb[8];
  float dot = 0.f;
#pragma unroll
  for (int j = 0; j < 8; ++j) {
    a[j] = f1[j] * inv1; bb[j] = f2[j] * inv2;
    dot += a[j] * bb[j];
  }
  int lo1 = __builtin_amdgcn_cvt_pk_fp8_f32(a[0], a[1], 0, false);
  lo1 = __builtin_amdgcn_cvt_pk_fp8_f32(a[2], a[3], lo1, true);
  int hi1 = __builtin_amdgcn_cvt_pk_fp8_f32(a[4], a[5], 0, false);
  hi1 = __builtin_amdgcn_cvt_pk_fp8_f32(a[6], a[7], hi1, true);
  int lo2 = __builtin_amdgcn_cvt_pk_fp8_f32(bb[0], bb[1], 0, false);
  lo2 = __builtin_amdgcn_cvt_pk_fp8_f32(bb[2], bb[3], lo2, true);
  int hi2 = __builtin_amdgcn_cvt_pk_fp8_f32(bb[4], bb[5], 0, false);
  hi2 = __builtin_amdgcn_cvt_pk_fp8_f32(bb[6], bb[7], hi2, true);
  *(int2*)(q1 + (size_t)row * 512 + lane * 8) = make_int2(lo1, hi1);
  *(int2*)(q2 + (size_t)row * 512 + lane * 8) = make_int2(lo2, hi2);
#pragma unroll
  for (int d = 1; d < 64; d <<= 1) dot += __shfl_xor(dot, d, 64);
  if (lane == 0) cdiag[row] = dot;
}

// ---------------- final scalar loss ----------------
__global__ __launch_bounds__(256)
void finalize_kernel(const float* __restrict__ d11, const float* __restrict__ d22,
                     const float* __restrict__ d12r, const float* __restrict__ d12c,
                     const float* __restrict__ cdiag, float* __restrict__ out) {
  const float e2 = 7.38905609893065f;
  float s = 0.f;
  for (int i = threadIdx.x; i < 8192; i += 256) {
    const float den1 = d11[i] + d12r[i] - e2;
    const float den2 = d22[i] + d12c[i] - e2;
    s += -2.0f * cdiag[i] + 0.5f * (logf(den1) + logf(den2));
  }
#pragma unroll
  for (int d = 1; d < 64; d <<= 1) s += __shfl_xor(s, d, 64);
  __shared__ float sm[4];
  if ((threadIdx.x & 63) == 0) sm[threadIdx.x >> 6] = s;
  __syncthreads();
  if (threadIdx.x == 0) out[0] = (sm[0] + sm[1] + sm[2] + sm[3]) * (1.0f / 8192.0f);
}

extern "C" void kernel_launch(void* const* d_in, const int* in_sizes, int n_in,
                              void* d_out, int out_size, void* d_ws, size_t ws_size,
                              hipStream_t stream) {
  const float* z1 = (const float*)d_in[0];
  const float* z2 = (const float*)d_in[1];
  const float* w1 = (const float*)d_in[2];
  const float* b1 = (const float*)d_in[3];
  const float* w2 = (const float*)d_in[4];
  const float* b2 = (const float*)d_in[5];
  float* out = (float*)d_out;

  const int N = 8192, D = 512;
  char* ws = (char*)d_ws;
  auto alloc = [&](size_t bytes) {
    char* p = ws; ws += (bytes + 255) & ~(size_t)255; return p;
  };
  unsigned short* z1b = (unsigned short*)alloc((size_t)N * D * 2);
  unsigned short* z2b = (unsigned short*)alloc((size_t)N * D * 2);
  unsigned short* g1  = (unsigned short*)alloc((size_t)N * D * 2);
  unsigned short* g2  = (unsigned short*)alloc((size_t)N * D * 2);
  unsigned short* w1b = (unsigned short*)alloc((size_t)D * D * 2);
  unsigned short* w2b = (unsigned short*)alloc((size_t)D * D * 2);
  float* sums  = (float*)alloc((size_t)4 * N * sizeof(float));
  float* cdiag = (float*)alloc((size_t)N * sizeof(float));
  float* d11 = sums, *d22 = sums + N, *d12r = sums + 2 * N, *d12c = sums + 3 * N;
  unsigned short* h1 = z1b;                 // stage-2 out aliases z buffers
  unsigned short* h2 = z2b;
  unsigned char* q1 = (unsigned char*)g1;   // fp8 aliases g (dead after proj2)
  unsigned char* q2 = (unsigned char*)g2;

  hipMemsetAsync(sums, 0, (size_t)4 * N * sizeof(float), stream);

  cast_all_kernel<<<dim3(8704), 256, 0, stream>>>(z1, z2, w1, w2, z1b, z2b, w1b, w2b);
  proj_kernel<0><<<dim3(512), 256, 0, stream>>>(z1b, z2b, w1b, b1, g1, g2);
  proj_kernel<1><<<dim3(512), 256, 0, stream>>>(g1, g2, w2b, b2, h1, h2);
  norm_diag_kernel<<<dim3(N / 4), 256, 0, stream>>>(h1, h2, q1, q2, cdiag);
  gram_kernel<<<dim3(1032), 256, 0, stream>>>(q1, q2, d11, d22, d12r, d12c);
  finalize_kernel<<<1, 256, 0, stream>>>(d11, d22, d12r, d12c, cdiag, out);
}

// Round 6
// 363.597 us; speedup vs baseline: 1.1443x; 1.0276x over previous
//
#include <hip/hip_runtime.h>
#include <math.h>

typedef __attribute__((ext_vector_type(8))) __bf16 bf16x8;
typedef __attribute__((ext_vector_type(4))) float f32x4;
typedef __attribute__((ext_vector_type(8))) unsigned short u16x8;
typedef __attribute__((ext_vector_type(8))) int i32x8;

#define GAS(p) ((const __attribute__((address_space(1))) void*)(p))
#define LAS(p) ((__attribute__((address_space(3))) void*)(p))

__device__ __forceinline__ unsigned short f2bf(float f) {
  union { float f; unsigned int u; } v; v.f = f;
  unsigned int r = (v.u + 0x7FFFu + ((v.u >> 16) & 1u)) >> 16;
  return (unsigned short)r;
}
__device__ __forceinline__ float bf2f(unsigned short b) {
  union { unsigned int u; float f; } v; v.u = ((unsigned int)b) << 16;
  return v.f;
}

// ---------------- fused f32 -> bf16 cast for z1,z2,w1,w2 ----------------
__global__ __launch_bounds__(256) void cast_all_kernel(
    const float* __restrict__ z1, const float* __restrict__ z2,
    const float* __restrict__ w1, const float* __restrict__ w2,
    unsigned short* __restrict__ z1b, unsigned short* __restrict__ z2b,
    unsigned short* __restrict__ w1b, unsigned short* __restrict__ w2b) {
  int b = blockIdx.x;
  const float* in; unsigned short* out; int base;
  if (b < 4096)       { in = z1; out = z1b; base = b; }
  else if (b < 8192)  { in = z2; out = z2b; base = b - 4096; }
  else if (b < 8448)  { in = w1; out = w1b; base = b - 8192; }
  else                { in = w2; out = w2b; base = b - 8448; }
  int i = (base * 256 + threadIdx.x) * 4;
  float4 v = *(const float4*)(in + i);
  ushort4 o;
  o.x = f2bf(v.x); o.y = f2bf(v.y); o.z = f2bf(v.z); o.w = f2bf(v.w);
  *(ushort4*)(out + i) = o;
}

// ---------------- core 128x128 NT bf16 tile, K=512 (projections) ----------------
__device__ __forceinline__ void gemm_tile_512(
    const unsigned short* __restrict__ A, const unsigned short* __restrict__ B,
    int m0, int n0, unsigned short* lA, unsigned short* lB, f32x4 acc[4][4]) {
  constexpr int K = 512;
  const int tid  = threadIdx.x;
  const int wave = tid >> 6;
  const int lane = tid & 63;
  const int quad = lane >> 4;
  const int l16  = lane & 15;
  const int wrow = (wave & 1) * 64;
  const int wcol = (wave >> 1) * 64;

  const f32x4 zero = {0.f, 0.f, 0.f, 0.f};
#pragma unroll
  for (int i = 0; i < 4; ++i)
#pragma unroll
    for (int j = 0; j < 4; ++j) acc[i][j] = zero;

  const int e0 = wave * 1024 + lane * 8;
  const int r0 = e0 >> 5, c0 = e0 & 31;
  const int e1 = e0 + 512;
  const int r1 = e1 >> 5, c1 = e1 & 31;

  const unsigned short* Ag0 = A + (size_t)(m0 + r0) * K + c0;
  const unsigned short* Ag1 = A + (size_t)(m0 + r1) * K + c1;
  const unsigned short* Bg0 = B + (size_t)(n0 + r0) * K + c0;
  const unsigned short* Bg1 = B + (size_t)(n0 + r1) * K + c1;

  for (int kt = 0; kt < K; kt += 32) {
    __syncthreads();
    __builtin_amdgcn_global_load_lds(GAS(Ag0 + kt), LAS(&lA[e0]), 16, 0, 0);
    __builtin_amdgcn_global_load_lds(GAS(Ag1 + kt), LAS(&lA[e1]), 16, 0, 0);
    __builtin_amdgcn_global_load_lds(GAS(Bg0 + kt), LAS(&lB[e0]), 16, 0, 0);
    __builtin_amdgcn_global_load_lds(GAS(Bg1 + kt), LAS(&lB[e1]), 16, 0, 0);
    __syncthreads();

    bf16x8 af[4], bfr[4];
#pragma unroll
    for (int i = 0; i < 4; ++i) {
      af[i]  = *(const bf16x8*)&lA[(wrow + i * 16 + l16) * 32 + quad * 8];
      bfr[i] = *(const bf16x8*)&lB[(wcol + i * 16 + l16) * 32 + quad * 8];
    }
#pragma unroll
    for (int mi = 0; mi < 4; ++mi)
#pragma unroll
      for (int ni = 0; ni < 4; ++ni)
        acc[mi][ni] = __builtin_amdgcn_mfma_f32_16x16x32_bf16(
            af[mi], bfr[ni], acc[mi][ni], 0, 0, 0);
  }
}

// ---------------- fused projection GEMM (2 inputs per launch) ----------------
template<int EPI>
__global__ __launch_bounds__(256)
void proj_kernel(const unsigned short* __restrict__ A1,
                 const unsigned short* __restrict__ A2,
                 const unsigned short* __restrict__ W,
                 const float* __restrict__ bias,
                 unsigned short* __restrict__ C1,
                 unsigned short* __restrict__ C2) {
  __shared__ unsigned short lA[128 * 32];
  __shared__ unsigned short lB[128 * 32];
  const int b = blockIdx.x;
  const int which = b >> 8;
  const int r = b & 255;
  const int n0 = (r & 3) * 128;
  const int m0 = (r >> 2) * 128;
  const unsigned short* A = which ? A2 : A1;
  unsigned short* C = which ? C2 : C1;

  f32x4 acc[4][4];
  gemm_tile_512(A, W, m0, n0, lA, lB, acc);

  const int lane = threadIdx.x & 63;
  const int wave = threadIdx.x >> 6;
  const int quad = lane >> 4;
  const int l16  = lane & 15;
  const int wrow = (wave & 1) * 64;
  const int wcol = (wave >> 1) * 64;

#pragma unroll
  for (int ni = 0; ni < 4; ++ni) {
    const int c = n0 + wcol + ni * 16 + l16;
    const float bv = bias[c];
#pragma unroll
    for (int mi = 0; mi < 4; ++mi) {
      const int rbase = m0 + wrow + mi * 16 + quad * 4;
#pragma unroll
      for (int rr = 0; rr < 4; ++rr) {
        float v = acc[mi][ni][rr] + bv;
        if constexpr (EPI == 0) v = (v > 0.f) ? v : expm1f(v);
        C[(size_t)(rbase + rr) * 512 + c] = f2bf(v);
      }
    }
  }
}

// ================= LDS-free, barrier-free MX-fp8 Gram kernel =================
// q1/q2 are stored in FRAGMENT-MAJOR layout (written by norm_diag_kernel):
// for 16-row panel p, k-chunk kt (128 cols), half h (16-byte half of each
// lane's 32 B), mfma-lane l = quad*16 + l16 (row=l16, k=quad*32+j):
//   byte addr = p*8192 + kt*2048 + h*1024 + l*16 + (j&15)
// So a fragment load is wave-uniform base + lane*16: one perfectly dense
// 1 KB global_load_dwordx4 (8 cache lines, 100% consumed). No LDS round
// trip, no __syncthreads, no vmcnt(0) drain: waves free-run with a register
// double-buffer over the 4 K-chunks.
__global__ __launch_bounds__(256)
void gram_kernel(const unsigned char* __restrict__ q1,
                 const unsigned char* __restrict__ q2,
                 float* __restrict__ d11, float* __restrict__ d22,
                 float* __restrict__ d12r, float* __restrict__ d12c) {
  const int b = blockIdx.x;
  const unsigned char *A, *B;
  float *rsum, *csum;
  int m0, n0;
  if (b < 4160) {
    const bool first = (b < 2080);
    const unsigned char* h = first ? q1 : q2;
    float* d = first ? d11 : d22;
    int t = first ? b : b - 2080;
    int by = (int)((sqrtf(8.f * t + 1.f) - 1.f) * 0.5f);
    while ((by + 1) * (by + 2) / 2 <= t) ++by;
    while (by * (by + 1) / 2 > t) --by;
    int bx = t - by * (by + 1) / 2;
    A = h; B = h; m0 = by * 128; n0 = bx * 128;
    rsum = d; csum = (bx == by) ? nullptr : d;
  } else {
    int t = b - 4160;
    m0 = (t >> 6) * 128; n0 = (t & 63) * 128;
    A = q1; B = q2; rsum = d12r; csum = d12c;
  }

  const int tid  = threadIdx.x;
  const int wave = tid >> 6;
  const int lane = tid & 63;
  const int quad = lane >> 4;
  const int l16  = lane & 15;
  const int wrow = (wave & 1) * 64;
  const int wcol = (wave >> 1) * 64;

  const f32x4 zero = {0.f, 0.f, 0.f, 0.f};
  f32x4 acc[4][4];
#pragma unroll
  for (int i = 0; i < 4; ++i)
#pragma unroll
    for (int j = 0; j < 4; ++j) acc[i][j] = zero;

  // fragment base pointers: panel (m0+wrow)/16 + i  ->  (m0+wrow+i*16)*512
  const unsigned char* Ap[4];
  const unsigned char* Bp[4];
#pragma unroll
  for (int i = 0; i < 4; ++i) {
    Ap[i] = A + (size_t)(m0 + wrow + i * 16) * 512 + lane * 16;
    Bp[i] = B + (size_t)(n0 + wcol + i * 16) * 512 + lane * 16;
  }

  union frag { i32x8 v; int4 h[2]; };
  frag fa[2][4], fb[2][4];

  // prologue: chunk 0 into buffer 0
#pragma unroll
  for (int i = 0; i < 4; ++i) {
    fa[0][i].h[0] = *(const int4*)(Ap[i]);
    fa[0][i].h[1] = *(const int4*)(Ap[i] + 1024);
    fb[0][i].h[0] = *(const int4*)(Bp[i]);
    fb[0][i].h[1] = *(const int4*)(Bp[i] + 1024);
  }

#pragma unroll
  for (int c = 0; c < 4; ++c) {
    const int cur = c & 1, nxt = cur ^ 1;
    if (c < 3) {
      const int off = (c + 1) * 2048;
#pragma unroll
      for (int i = 0; i < 4; ++i) {
        fa[nxt][i].h[0] = *(const int4*)(Ap[i] + off);
        fa[nxt][i].h[1] = *(const int4*)(Ap[i] + off + 1024);
        fb[nxt][i].h[0] = *(const int4*)(Bp[i] + off);
        fb[nxt][i].h[1] = *(const int4*)(Bp[i] + off + 1024);
      }
    }
#pragma unroll
    for (int mi = 0; mi < 4; ++mi)
#pragma unroll
      for (int ni = 0; ni < 4; ++ni)
        acc[mi][ni] = __builtin_amdgcn_mfma_scale_f32_16x16x128_f8f6f4(
            fa[cur][mi].v, fb[cur][ni].v, acc[mi][ni],
            0, 0,                    // cbsz=e4m3, blgp=e4m3
            0, 0x7F7F7F7F,           // scale_a (E8M0 1.0)
            0, 0x7F7F7F7F);          // scale_b
  }

  // epilogue: C/D layout shape-determined: col=lane&15, row=quad*4+reg
  float cs[4] = {0.f, 0.f, 0.f, 0.f};
#pragma unroll
  for (int mi = 0; mi < 4; ++mi) {
    float rs[4] = {0.f, 0.f, 0.f, 0.f};
#pragma unroll
    for (int ni = 0; ni < 4; ++ni) {
#pragma unroll
      for (int rr = 0; rr < 4; ++rr) {
        float v = __expf(2.0f * acc[mi][ni][rr]);
        rs[rr] += v;
        cs[ni] += v;
      }
    }
#pragma unroll
    for (int d = 1; d < 16; d <<= 1) {
#pragma unroll
      for (int rr = 0; rr < 4; ++rr) rs[rr] += __shfl_xor(rs[rr], d, 64);
    }
    if (l16 == 0) {
      const int rbase = m0 + wrow + mi * 16 + quad * 4;
#pragma unroll
      for (int rr = 0; rr < 4; ++rr) atomicAdd(&rsum[rbase + rr], rs[rr]);
    }
  }
  if (csum) {
#pragma unroll
    for (int ni = 0; ni < 4; ++ni) {
      float v = cs[ni];
      v += __shfl_xor(v, 16, 64);
      v += __shfl_xor(v, 32, 64);
      if (quad == 0) atomicAdd(&csum[n0 + wcol + ni * 16 + l16], v);
    }
  }
}

// ---------------- normalize -> fp8 in FRAGMENT-MAJOR layout + diag dot ----------------
__global__ __launch_bounds__(256)
void norm_diag_kernel(const unsigned short* __restrict__ h1,
                      const unsigned short* __restrict__ h2,
                      unsigned char* __restrict__ q1,
                      unsigned char* __restrict__ q2,
                      float* __restrict__ cdiag) {
  const int wave = threadIdx.x >> 6, lane = threadIdx.x & 63;
  const int row = blockIdx.x * 4 + wave;
  const u16x8 u1 = *(const u16x8*)(h1 + (size_t)row * 512 + lane * 8);
  const u16x8 u2 = *(const u16x8*)(h2 + (size_t)row * 512 + lane * 8);
  float f1[8], f2[8], ss1 = 0.f, ss2 = 0.f;
#pragma unroll
  for (int j = 0; j < 8; ++j) {
    f1[j] = bf2f(u1[j]); ss1 += f1[j] * f1[j];
    f2[j] = bf2f(u2[j]); ss2 += f2[j] * f2[j];
  }
#pragma unroll
  for (int d = 1; d < 64; d <<= 1) {
    ss1 += __shfl_xor(ss1, d, 64);
    ss2 += __shfl_xor(ss2, d, 64);
  }
  const float inv1 = 1.0f / fmaxf(sqrtf(ss1), 1e-12f);
  const float inv2 = 1.0f / fmaxf(sqrtf(ss2), 1e-12f);
  float a[8], bb[8];
  float dot = 0.f;
#pragma unroll
  for (int j = 0; j < 8; ++j) {
    a[j] = f1[j] * inv1; bb[j] = f2[j] * inv2;
    dot += a[j] * bb[j];
  }
  int lo1 = __builtin_amdgcn_cvt_pk_fp8_f32(a[0], a[1], 0, false);
  lo1 = __builtin_amdgcn_cvt_pk_fp8_f32(a[2], a[3], lo1, true);
  int hi1 = __builtin_amdgcn_cvt_pk_fp8_f32(a[4], a[5], 0, false);
  hi1 = __builtin_amdgcn_cvt_pk_fp8_f32(a[6], a[7], hi1, true);
  int lo2 = __builtin_amdgcn_cvt_pk_fp8_f32(bb[0], bb[1], 0, false);
  lo2 = __builtin_amdgcn_cvt_pk_fp8_f32(bb[2], bb[3], lo2, true);
  int hi2 = __builtin_amdgcn_cvt_pk_fp8_f32(bb[4], bb[5], 0, false);
  hi2 = __builtin_amdgcn_cvt_pk_fp8_f32(bb[6], bb[7], hi2, true);

  // fragment-major destination for this lane's 8 bytes (cols c0..c0+7):
  // p=row>>4, kt=c0>>7, quad=(c0>>5)&3, j0=c0&31, half=j0>>4
  const int c0 = lane * 8;
  const int kt = c0 >> 7;
  const int qd = (c0 >> 5) & 3;
  const int j0 = c0 & 31;
  const size_t dst = (size_t)(row >> 4) * 8192 + kt * 2048 + (j0 >> 4) * 1024
                   + (qd * 16 + (row & 15)) * 16 + (j0 & 15);
  *(int2*)(q1 + dst) = make_int2(lo1, hi1);
  *(int2*)(q2 + dst) = make_int2(lo2, hi2);
#pragma unroll
  for (int d = 1; d < 64; d <<= 1) dot += __shfl_xor(dot, d, 64);
  if (lane == 0) cdiag[row] = dot;
}

// ---------------- final scalar loss ----------------
__global__ __launch_bounds__(256)
void finalize_kernel(const float* __restrict__ d11, const float* __restrict__ d22,
                     const float* __restrict__ d12r, const float* __restrict__ d12c,
                     const float* __restrict__ cdiag, float* __restrict__ out) {
  const float e2 = 7.38905609893065f;
  float s = 0.f;
  for (int i = threadIdx.x; i < 8192; i += 256) {
    const float den1 = d11[i] + d12r[i] - e2;
    const float den2 = d22[i] + d12c[i] - e2;
    s += -2.0f * cdiag[i] + 0.5f * (logf(den1) + logf(den2));
  }
#pragma unroll
  for (int d = 1; d < 64; d <<= 1) s += __shfl_xor(s, d, 64);
  __shared__ float sm[4];
  if ((threadIdx.x & 63) == 0) sm[threadIdx.x >> 6] = s;
  __syncthreads();
  if (threadIdx.x == 0) out[0] = (sm[0] + sm[1] + sm[2] + sm[3]) * (1.0f / 8192.0f);
}

extern "C" void kernel_launch(void* const* d_in, const int* in_sizes, int n_in,
                              void* d_out, int out_size, void* d_ws, size_t ws_size,
                              hipStream_t stream) {
  const float* z1 = (const float*)d_in[0];
  const float* z2 = (const float*)d_in[1];
  const float* w1 = (const float*)d_in[2];
  const float* b1 = (const float*)d_in[3];
  const float* w2 = (const float*)d_in[4];
  const float* b2 = (const float*)d_in[5];
  float* out = (float*)d_out;

  const int N = 8192, D = 512;
  char* ws = (char*)d_ws;
  auto alloc = [&](size_t bytes) {
    char* p = ws; ws += (bytes + 255) & ~(size_t)255; return p;
  };
  unsigned short* z1b = (unsigned short*)alloc((size_t)N * D * 2);
  unsigned short* z2b = (unsigned short*)alloc((size_t)N * D * 2);
  unsigned short* g1  = (unsigned short*)alloc((size_t)N * D * 2);
  unsigned short* g2  = (unsigned short*)alloc((size_t)N * D * 2);
  unsigned short* w1b = (unsigned short*)alloc((size_t)D * D * 2);
  unsigned short* w2b = (unsigned short*)alloc((size_t)D * D * 2);
  float* sums  = (float*)alloc((size_t)4 * N * sizeof(float));
  float* cdiag = (float*)alloc((size_t)N * sizeof(float));
  float* d11 = sums, *d22 = sums + N, *d12r = sums + 2 * N, *d12c = sums + 3 * N;
  unsigned short* h1 = z1b;                 // stage-2 out aliases z buffers
  unsigned short* h2 = z2b;
  unsigned char* q1 = (unsigned char*)g1;   // fp8 aliases g (dead after proj2)
  unsigned char* q2 = (unsigned char*)g2;

  hipMemsetAsync(sums, 0, (size_t)4 * N * sizeof(float), stream);

  cast_all_kernel<<<dim3(8704), 256, 0, stream>>>(z1, z2, w1, w2, z1b, z2b, w1b, w2b);
  proj_kernel<0><<<dim3(512), 256, 0, stream>>>(z1b, z2b, w1b, b1, g1, g2);
  proj_kernel<1><<<dim3(512), 256, 0, stream>>>(g1, g2, w2b, b2, h1, h2);
  norm_diag_kernel<<<dim3(N / 4), 256, 0, stream>>>(h1, h2, q1, q2, cdiag);
  gram_kernel<<<dim3(8256), 256, 0, stream>>>(q1, q2, d11, d22, d12r, d12c);
  finalize_kernel<<<1, 256, 0, stream>>>(d11, d22, d12r, d12c, cdiag, out);
}

// Round 7
// 300.319 us; speedup vs baseline: 1.3854x; 1.2107x over previous
//
#include <hip/hip_runtime.h>
#include <math.h>

typedef __attribute__((ext_vector_type(8))) __bf16 bf16x8;
typedef __attribute__((ext_vector_type(4))) float f32x4;
typedef __attribute__((ext_vector_type(8))) unsigned short u16x8;
typedef __attribute__((ext_vector_type(8))) int i32x8;

#define GAS(p) ((const __attribute__((address_space(1))) void*)(p))
#define LAS(p) ((__attribute__((address_space(3))) void*)(p))

__device__ __forceinline__ unsigned short f2bf(float f) {
  union { float f; unsigned int u; } v; v.f = f;
  unsigned int r = (v.u + 0x7FFFu + ((v.u >> 16) & 1u)) >> 16;
  return (unsigned short)r;
}
__device__ __forceinline__ float bf2f(unsigned short b) {
  union { unsigned int u; float f; } v; v.u = ((unsigned int)b) << 16;
  return v.f;
}

// ---------------- fused f32 -> bf16 cast for z1,z2,w1,w2 ----------------
__global__ __launch_bounds__(256) void cast_all_kernel(
    const float* __restrict__ z1, const float* __restrict__ z2,
    const float* __restrict__ w1, const float* __restrict__ w2,
    unsigned short* __restrict__ z1b, unsigned short* __restrict__ z2b,
    unsigned short* __restrict__ w1b, unsigned short* __restrict__ w2b) {
  int b = blockIdx.x;
  const float* in; unsigned short* out; int base;
  if (b < 4096)       { in = z1; out = z1b; base = b; }
  else if (b < 8192)  { in = z2; out = z2b; base = b - 4096; }
  else if (b < 8448)  { in = w1; out = w1b; base = b - 8192; }
  else                { in = w2; out = w2b; base = b - 8448; }
  int i = (base * 256 + threadIdx.x) * 4;
  float4 v = *(const float4*)(in + i);
  ushort4 o;
  o.x = f2bf(v.x); o.y = f2bf(v.y); o.z = f2bf(v.z); o.w = f2bf(v.w);
  *(ushort4*)(out + i) = o;
}

// ---------------- core 128x128 NT bf16 tile, K=512 (projections) ----------------
__device__ __forceinline__ void gemm_tile_512(
    const unsigned short* __restrict__ A, const unsigned short* __restrict__ B,
    int m0, int n0, unsigned short* lA, unsigned short* lB, f32x4 acc[4][4]) {
  constexpr int K = 512;
  const int tid  = threadIdx.x;
  const int wave = tid >> 6;
  const int lane = tid & 63;
  const int quad = lane >> 4;
  const int l16  = lane & 15;
  const int wrow = (wave & 1) * 64;
  const int wcol = (wave >> 1) * 64;

  const f32x4 zero = {0.f, 0.f, 0.f, 0.f};
#pragma unroll
  for (int i = 0; i < 4; ++i)
#pragma unroll
    for (int j = 0; j < 4; ++j) acc[i][j] = zero;

  const int e0 = wave * 1024 + lane * 8;
  const int r0 = e0 >> 5, c0 = e0 & 31;
  const int e1 = e0 + 512;
  const int r1 = e1 >> 5, c1 = e1 & 31;

  const unsigned short* Ag0 = A + (size_t)(m0 + r0) * K + c0;
  const unsigned short* Ag1 = A + (size_t)(m0 + r1) * K + c1;
  const unsigned short* Bg0 = B + (size_t)(n0 + r0) * K + c0;
  const unsigned short* Bg1 = B + (size_t)(n0 + r1) * K + c1;

  for (int kt = 0; kt < K; kt += 32) {
    __syncthreads();
    __builtin_amdgcn_global_load_lds(GAS(Ag0 + kt), LAS(&lA[e0]), 16, 0, 0);
    __builtin_amdgcn_global_load_lds(GAS(Ag1 + kt), LAS(&lA[e1]), 16, 0, 0);
    __builtin_amdgcn_global_load_lds(GAS(Bg0 + kt), LAS(&lB[e0]), 16, 0, 0);
    __builtin_amdgcn_global_load_lds(GAS(Bg1 + kt), LAS(&lB[e1]), 16, 0, 0);
    __syncthreads();

    bf16x8 af[4], bfr[4];
#pragma unroll
    for (int i = 0; i < 4; ++i) {
      af[i]  = *(const bf16x8*)&lA[(wrow + i * 16 + l16) * 32 + quad * 8];
      bfr[i] = *(const bf16x8*)&lB[(wcol + i * 16 + l16) * 32 + quad * 8];
    }
#pragma unroll
    for (int mi = 0; mi < 4; ++mi)
#pragma unroll
      for (int ni = 0; ni < 4; ++ni)
        acc[mi][ni] = __builtin_amdgcn_mfma_f32_16x16x32_bf16(
            af[mi], bfr[ni], acc[mi][ni], 0, 0, 0);
  }
}

// ---------------- fused projection GEMM (2 inputs per launch) ----------------
template<int EPI>
__global__ __launch_bounds__(256)
void proj_kernel(const unsigned short* __restrict__ A1,
                 const unsigned short* __restrict__ A2,
                 const unsigned short* __restrict__ W,
                 const float* __restrict__ bias,
                 unsigned short* __restrict__ C1,
                 unsigned short* __restrict__ C2) {
  __shared__ unsigned short lA[128 * 32];
  __shared__ unsigned short lB[128 * 32];
  const int b = blockIdx.x;
  const int which = b >> 8;
  const int r = b & 255;
  const int n0 = (r & 3) * 128;
  const int m0 = (r >> 2) * 128;
  const unsigned short* A = which ? A2 : A1;
  unsigned short* C = which ? C2 : C1;

  f32x4 acc[4][4];
  gemm_tile_512(A, W, m0, n0, lA, lB, acc);

  const int lane = threadIdx.x & 63;
  const int wave = threadIdx.x >> 6;
  const int quad = lane >> 4;
  const int l16  = lane & 15;
  const int wrow = (wave & 1) * 64;
  const int wcol = (wave >> 1) * 64;

#pragma unroll
  for (int ni = 0; ni < 4; ++ni) {
    const int c = n0 + wcol + ni * 16 + l16;
    const float bv = bias[c];
#pragma unroll
    for (int mi = 0; mi < 4; ++mi) {
      const int rbase = m0 + wrow + mi * 16 + quad * 4;
#pragma unroll
      for (int rr = 0; rr < 4; ++rr) {
        float v = acc[mi][ni][rr] + bv;
        if constexpr (EPI == 0) v = (v > 0.f) ? v : expm1f(v);
        C[(size_t)(rbase + rr) * 512 + c] = f2bf(v);
      }
    }
  }
}

// ---------------- fused MX-fp8 Gram kernel (R2 structure, 3 waves/EU) ------
// blocks [0,2080): lower-tri of q1 q1^T -> d11 ; [2080,4160): q2 q2^T -> d22
// blocks [4160,8256): full q1 q2^T -> d12r/d12c
// __launch_bounds__(256,3): force V+A register budget <= ~170 so 3 blocks/CU
// co-reside (R2 measured 2 blocks/CU at 124V+64A; min live set ~158).
__global__ __launch_bounds__(256, 3)
void gram_kernel(const unsigned char* __restrict__ q1,
                 const unsigned char* __restrict__ q2,
                 float* __restrict__ d11, float* __restrict__ d22,
                 float* __restrict__ d12r, float* __restrict__ d12c) {
  __shared__ unsigned char lA[128 * 128];
  __shared__ unsigned char lB[128 * 128];

  const int b = blockIdx.x;
  const unsigned char *A, *B;
  float *rsum, *csum;
  int m0, n0;
  if (b < 4160) {
    const bool first = (b < 2080);
    const unsigned char* h = first ? q1 : q2;
    float* d = first ? d11 : d22;
    int t = first ? b : b - 2080;
    int by = (int)((sqrtf(8.f * t + 1.f) - 1.f) * 0.5f);
    while ((by + 1) * (by + 2) / 2 <= t) ++by;
    while (by * (by + 1) / 2 > t) --by;
    int bx = t - by * (by + 1) / 2;
    A = h; B = h; m0 = by * 128; n0 = bx * 128;
    rsum = d; csum = (bx == by) ? nullptr : d;
  } else {
    int t = b - 4160;
    m0 = (t >> 6) * 128; n0 = (t & 63) * 128;
    A = q1; B = q2; rsum = d12r; csum = d12c;
  }

  const int tid  = threadIdx.x;
  const int wave = tid >> 6;
  const int lane = tid & 63;
  const int quad = lane >> 4;
  const int l16  = lane & 15;
  const int wrow = (wave & 1) * 64;
  const int wcol = (wave >> 1) * 64;

  const f32x4 zero = {0.f, 0.f, 0.f, 0.f};
  f32x4 acc[4][4];
#pragma unroll
  for (int i = 0; i < 4; ++i)
#pragma unroll
    for (int j = 0; j < 4; ++j) acc[i][j] = zero;

  // staging: inst t, lane l -> phys LDS wave*4096 + t*1024 + l*16
  // phys row = wave*32 + t*8 + (l>>3); phys block = l&7;
  // logical (source) block = (l&7) ^ ((l>>3)&7)   (XOR swizzle)
  const int srow = wave * 32 + (lane >> 3);
  const int sblk = (lane & 7) ^ ((lane >> 3) & 7);
  const unsigned char* Ab = A + (size_t)(m0 + srow) * 512 + sblk * 16;
  const unsigned char* Bb = B + (size_t)(n0 + srow) * 512 + sblk * 16;
  const int ldst = wave * 4096 + lane * 16;

  union frag { i32x8 v; int4 h[2]; };

  for (int kt = 0; kt < 512; kt += 128) {
    __syncthreads();
#pragma unroll
    for (int t = 0; t < 4; ++t) {
      __builtin_amdgcn_global_load_lds(GAS(Ab + kt + t * 8 * 512),
                                       LAS(&lA[ldst + t * 1024]), 16, 0, 0);
      __builtin_amdgcn_global_load_lds(GAS(Bb + kt + t * 8 * 512),
                                       LAS(&lB[ldst + t * 1024]), 16, 0, 0);
    }
    __syncthreads();

    // A-operand layout (verified 16x16x128): row=lane&15, k = quad*32 + j
    frag fa[4], fb[4];
#pragma unroll
    for (int i = 0; i < 4; ++i) {
      const int ra = wrow + i * 16 + l16;
      const int pa = ra & 7;
      fa[i].h[0] = *(const int4*)&lA[ra * 128 + ((2 * quad)     ^ pa) * 16];
      fa[i].h[1] = *(const int4*)&lA[ra * 128 + ((2 * quad + 1) ^ pa) * 16];
      const int rb = wcol + i * 16 + l16;
      const int pb = rb & 7;
      fb[i].h[0] = *(const int4*)&lB[rb * 128 + ((2 * quad)     ^ pb) * 16];
      fb[i].h[1] = *(const int4*)&lB[rb * 128 + ((2 * quad + 1) ^ pb) * 16];
    }
#pragma unroll
    for (int mi = 0; mi < 4; ++mi)
#pragma unroll
      for (int ni = 0; ni < 4; ++ni)
        acc[mi][ni] = __builtin_amdgcn_mfma_scale_f32_16x16x128_f8f6f4(
            fa[mi].v, fb[ni].v, acc[mi][ni],
            0, 0,                    // cbsz=e4m3, blgp=e4m3
            0, 0x7F7F7F7F,           // scale_a (E8M0 1.0)
            0, 0x7F7F7F7F);          // scale_b
  }

  // epilogue: C/D layout shape-determined: col=lane&15, row=quad*4+reg
  float cs[4] = {0.f, 0.f, 0.f, 0.f};
#pragma unroll
  for (int mi = 0; mi < 4; ++mi) {
    float rs[4] = {0.f, 0.f, 0.f, 0.f};
#pragma unroll
    for (int ni = 0; ni < 4; ++ni) {
#pragma unroll
      for (int rr = 0; rr < 4; ++rr) {
        float v = __expf(2.0f * acc[mi][ni][rr]);
        rs[rr] += v;
        cs[ni] += v;
      }
    }
#pragma unroll
    for (int d = 1; d < 16; d <<= 1) {
#pragma unroll
      for (int rr = 0; rr < 4; ++rr) rs[rr] += __shfl_xor(rs[rr], d, 64);
    }
    if (l16 == 0) {
      const int rbase = m0 + wrow + mi * 16 + quad * 4;
#pragma unroll
      for (int rr = 0; rr < 4; ++rr) atomicAdd(&rsum[rbase + rr], rs[rr]);
    }
  }
  if (csum) {
#pragma unroll
    for (int ni = 0; ni < 4; ++ni) {
      float v = cs[ni];
      v += __shfl_xor(v, 16, 64);
      v += __shfl_xor(v, 32, 64);
      if (quad == 0) atomicAdd(&csum[n0 + wcol + ni * 16 + l16], v);
    }
  }
}

// ---------------- normalize -> fp8 (q1,q2) + diag dot ----------------
__global__ __launch_bounds__(256)
void norm_diag_kernel(const unsigned short* __restrict__ h1,
                      const unsigned short* __restrict__ h2,
                      unsigned char* __restrict__ q1,
                      unsigned char* __restrict__ q2,
                      float* __restrict__ cdiag) {
  const int wave = threadIdx.x >> 6, lane = threadIdx.x & 63;
  const int row = blockIdx.x * 4 + wave;
  const u16x8 u1 = *(const u16x8*)(h1 + (size_t)row * 512 + lane * 8);
  const u16x8 u2 = *(const u16x8*)(h2 + (size_t)row * 512 + lane * 8);
  float f1[8], f2[8], ss1 = 0.f, ss2 = 0.f;
#pragma unroll
  for (int j = 0; j < 8; ++j) {
    f1[j] = bf2f(u1[j]); ss1 += f1[j] * f1[j];
    f2[j] = bf2f(u2[j]); ss2 += f2[j] * f2[j];
  }
#pragma unroll
  for (int d = 1; d < 64; d <<= 1) {
    ss1 += __shfl_xor(ss1, d, 64);
    ss2 += __shfl_xor(ss2, d, 64);
  }
  const float inv1 = 1.0f / fmaxf(sqrtf(ss1), 1e-12f);
  const float inv2 = 1.0f / fmaxf(sqrtf(ss2), 1e-12f);
  float a[8], bb[8];
  float dot = 0.f;
#pragma unroll
  for (int j = 0; j < 8; ++j) {
    a[j] = f1[j] * inv1; bb[j] = f2[j] * inv2;
    dot += a[j] * bb[j];
  }
  int lo1 = __builtin_amdgcn_cvt_pk_fp8_f32(a[0], a[1], 0, false);
  lo1 = __builtin_amdgcn_cvt_pk_fp8_f32(a[2], a[3], lo1, true);
  int hi1 = __builtin_amdgcn_cvt_pk_fp8_f32(a[4], a[5], 0, false);
  hi1 = __builtin_amdgcn_cvt_pk_fp8_f32(a[6], a[7], hi1, true);
  int lo2 = __builtin_amdgcn_cvt_pk_fp8_f32(bb[0], bb[1], 0, false);
  lo2 = __builtin_amdgcn_cvt_pk_fp8_f32(bb[2], bb[3], lo2, true);
  int hi2 = __builtin_amdgcn_cvt_pk_fp8_f32(bb[4], bb[5], 0, false);
  hi2 = __builtin_amdgcn_cvt_pk_fp8_f32(bb[6], bb[7], hi2, true);
  *(int2*)(q1 + (size_t)row * 512 + lane * 8) = make_int2(lo1, hi1);
  *(int2*)(q2 + (size_t)row * 512 + lane * 8) = make_int2(lo2, hi2);
#pragma unroll
  for (int d = 1; d < 64; d <<= 1) dot += __shfl_xor(dot, d, 64);
  if (lane == 0) cdiag[row] = dot;
}

// ---------------- final scalar loss ----------------
__global__ __launch_bounds__(256)
void finalize_kernel(const float* __restrict__ d11, const float* __restrict__ d22,
                     const float* __restrict__ d12r, const float* __restrict__ d12c,
                     const float* __restrict__ cdiag, float* __restrict__ out) {
  const float e2 = 7.38905609893065f;
  float s = 0.f;
  for (int i = threadIdx.x; i < 8192; i += 256) {
    const float den1 = d11[i] + d12r[i] - e2;
    const float den2 = d22[i] + d12c[i] - e2;
    s += -2.0f * cdiag[i] + 0.5f * (logf(den1) + logf(den2));
  }
#pragma unroll
  for (int d = 1; d < 64; d <<= 1) s += __shfl_xor(s, d, 64);
  __shared__ float sm[4];
  if ((threadIdx.x & 63) == 0) sm[threadIdx.x >> 6] = s;
  __syncthreads();
  if (threadIdx.x == 0) out[0] = (sm[0] + sm[1] + sm[2] + sm[3]) * (1.0f / 8192.0f);
}

extern "C" void kernel_launch(void* const* d_in, const int* in_sizes, int n_in,
                              void* d_out, int out_size, void* d_ws, size_t ws_size,
                              hipStream_t stream) {
  const float* z1 = (const float*)d_in[0];
  const float* z2 = (const float*)d_in[1];
  const float* w1 = (const float*)d_in[2];
  const float* b1 = (const float*)d_in[3];
  const float* w2 = (const float*)d_in[4];
  const float* b2 = (const float*)d_in[5];
  float* out = (float*)d_out;

  const int N = 8192, D = 512;
  char* ws = (char*)d_ws;
  auto alloc = [&](size_t bytes) {
    char* p = ws; ws += (bytes + 255) & ~(size_t)255; return p;
  };
  unsigned short* z1b = (unsigned short*)alloc((size_t)N * D * 2);
  unsigned short* z2b = (unsigned short*)alloc((size_t)N * D * 2);
  unsigned short* g1  = (unsigned short*)alloc((size_t)N * D * 2);
  unsigned short* g2  = (unsigned short*)alloc((size_t)N * D * 2);
  unsigned short* w1b = (unsigned short*)alloc((size_t)D * D * 2);
  unsigned short* w2b = (unsigned short*)alloc((size_t)D * D * 2);
  float* sums  = (float*)alloc((size_t)4 * N * sizeof(float));
  float* cdiag = (float*)alloc((size_t)N * sizeof(float));
  float* d11 = sums, *d22 = sums + N, *d12r = sums + 2 * N, *d12c = sums + 3 * N;
  unsigned short* h1 = z1b;                 // stage-2 out aliases z buffers
  unsigned short* h2 = z2b;
  unsigned char* q1 = (unsigned char*)g1;   // fp8 aliases g (dead after proj2)
  unsigned char* q2 = (unsigned char*)g2;

  hipMemsetAsync(sums, 0, (size_t)4 * N * sizeof(float), stream);

  cast_all_kernel<<<dim3(8704), 256, 0, stream>>>(z1, z2, w1, w2, z1b, z2b, w1b, w2b);
  proj_kernel<0><<<dim3(512), 256, 0, stream>>>(z1b, z2b, w1b, b1, g1, g2);
  proj_kernel<1><<<dim3(512), 256, 0, stream>>>(g1, g2, w2b, b2, h1, h2);
  norm_diag_kernel<<<dim3(N / 4), 256, 0, stream>>>(h1, h2, q1, q2, cdiag);
  gram_kernel<<<dim3(8256), 256, 0, stream>>>(q1, q2, d11, d22, d12r, d12c);
  finalize_kernel<<<1, 256, 0, stream>>>(d11, d22, d12r, d12c, cdiag, out);
}